// Round 14
// baseline (130.723 us; speedup 1.0000x reference)
//
#include <hip/hip_runtime.h>
#include <math.h>

#define M_GRID 128
#define J_FEAT 80
#define NNET   160   // NBASE*J_FEAT
#define HDIM   256

typedef __attribute__((ext_vector_type(8))) short v8s;   // 8 bf16
typedef __attribute__((ext_vector_type(4))) float f4;    // MFMA accum / float4

__device__ __forceinline__ unsigned short f2bf(float f) {
    unsigned u = __float_as_uint(f);
    u += 0x7fffu + ((u >> 16) & 1u);   // round-to-nearest-even
    return (unsigned short)(u >> 16);
}

__device__ __forceinline__ float selu_f(float x) {
    const float SC = 1.0507009873554805f;
    const float AL = 1.6732632423543772f;
    return x > 0.f ? SC * x : SC * AL * (__expf(x) - 1.f);
}

#define FENCE_BAR() do { asm volatile("s_waitcnt lgkmcnt(0)" ::: "memory"); \
                         __builtin_amdgcn_sched_barrier(0);                 \
                         __builtin_amdgcn_s_barrier(); } while (0)

// One workgroup per network n. 512 threads = 8 waves, wave w owns rows
// 16w..16w+15.  Synthesis of rounds 1-13:
//  - global_load_lds from L3-resident source is latency-walled (~11 GB/s/CU,
//    r5-r10); ordinary VMEM scales with outstanding lines (fillBuffer 27
//    GB/s/CU) -> stage W via VMEM register sets (r9 schedule).
//  - r9's only failure was spill: afrag[8] (32 regs) + rr pushed past the
//    128 budget.  Fix: act lives in LDS (r10), afrag deleted; and
//    waves_per_eu(2,2) grants the 256-reg unified budget (r7-proven at 2
//    waves/SIMD).  Only long-lived state: acc[16] in AGPRs + rr[2][16].
//  - One barrier per K-stage, all waits compiler-counted on exact registers,
//    pipeline continuous across layers (issue(q+2) crosses layer bounds and
//    flies during the epilogue).
// LDS 110 KB: bf16 tiles 2x16K @0, act @32K (8 waves x 8K, wave-private,
// XOR-swizzled), params @96K (14 KB).
__attribute__((amdgpu_flat_work_group_size(512, 512), amdgpu_waves_per_eu(2, 2)))
__global__ void basis_kernel(const float* __restrict__ t,
                             const float* __restrict__ W_in,
                             const float* __restrict__ b_in,
                             const float* __restrict__ W_h,
                             const float* __restrict__ b_h,
                             const float* __restrict__ W_out,
                             const float* __restrict__ b_out,
                             const float* __restrict__ ln_a,
                             const float* __restrict__ ln_b,
                             float* __restrict__ basesT)   // [M][NNET]
{
    extern __shared__ __align__(16) unsigned char lds[];   // 112640 B
    const int n    = blockIdx.x;
    const int tid  = threadIdx.x;
    const int l    = tid & 63;
    const int wv   = tid >> 6;      // wave 0..7
    const int lr   = l & 15;
    const int g    = l >> 4;        // k-group
    const int jcol = tid & 255;     // staging column
    const int o8   = tid >> 8;      // staging k-half (0/1)

    unsigned char* const actw = lds + 32768 + (size_t)wv * 8192;
    float* const P = (float*)(lds + 98304);
    // P groups (256 floats): 0=wo, 1-3=ln_a L1..3, 4-6=ln_b L1..3,
    // 7-9=b_h L0..2, 10=wi, 11=bi, 12=ln_a L0, 13=ln_b L0.

    // -------- staging helpers (r9-proven layout/swizzle/schedule) --------
    float rr[2][16];
    auto issue = [&](float (&r)[16], int q) {   // q = global stage 0..23
        const float* Wq = W_h + ((size_t)((q >> 3) * NNET + n) << 16)
                        + (size_t)((q & 7) * 32 + o8 * 16) * HDIM + jcol;
        #pragma unroll
        for (int i = 0; i < 16; ++i) r[i] = Wq[(size_t)i * HDIM];
    };
    auto convert_store = [&](float (&r)[16], int bufp) {
        #pragma unroll
        for (int o = 0; o < 2; ++o) {
            v8s pk;
            #pragma unroll
            for (int i = 0; i < 8; ++i) pk[i] = (short)f2bf(r[o * 8 + i]);
            int byte = (bufp << 14) + (o8 << 13) + jcol * 32 + (o << 4);
            byte ^= ((jcol >> 2) & 7) << 4;
            *(v8s*)(lds + byte) = pk;
        }
    };

    issue(rr[0], 0);        // in flight during param staging + input layer
    issue(rr[1], 1);

    // -------- params -> LDS --------
    {
        const size_t nb = (size_t)n * HDIM;
        #pragma unroll
        for (int i = 0; i < 7; ++i) {
            const int idx = tid + (i << 9), grp = idx >> 8, off = idx & 255;
            float v;
            if (grp == 0)       v = W_out[nb + off];
            else if (grp < 4)   v = ln_a[((size_t)grp * NNET + n) * HDIM + off];
            else if (grp < 7)   v = ln_b[((size_t)(grp - 3) * NNET + n) * HDIM + off];
            else if (grp < 10)  v = b_h[((size_t)(grp - 7) * NNET + n) * HDIM + off];
            else if (grp == 10) v = W_in[nb + off];
            else if (grp == 11) v = b_in[nb + off];
            else if (grp == 12) v = ln_a[nb + off];
            else                v = ln_b[nb + off];
            P[idx] = v;
        }
    }
    FENCE_BAR();   // params visible (raw barrier: rr loads stay in flight)

    // -------- input layer (LDS params; two passes; output straight to act) ----
    const float tval = t[wv * 16 + lr];
    {
        const float* wi = P + 2560; const float* bi = P + 2816;
        const float* la = P + 3072; const float* lb = P + 3328;
        float s_ = 0.f, q_ = 0.f;
        #pragma unroll
        for (int kt = 0; kt < 8; ++kt) {
            const int h0 = kt * 32 + g * 8;
            const f4 w0 = *(const f4*)(wi + h0), w1 = *(const f4*)(wi + h0 + 4);
            const f4 b0 = *(const f4*)(bi + h0), b1 = *(const f4*)(bi + h0 + 4);
            #pragma unroll
            for (int i = 0; i < 4; ++i) {
                float v0 = __builtin_fmaf(tval, w0[i], b0[i]);
                float v1 = __builtin_fmaf(tval, w1[i], b1[i]);
                s_ += v0 + v1; q_ += v0 * v0 + v1 * v1;
            }
        }
        s_ += __shfl_xor(s_, 16); q_ += __shfl_xor(q_, 16);
        s_ += __shfl_xor(s_, 32); q_ += __shfl_xor(q_, 32);
        const float mean = s_ * (1.f / 256.f);
        const float var  = (q_ - s_ * s_ * (1.f / 256.f)) * (1.f / 255.f); // unbiased
        const float inv  = 1.f / (sqrtf(var) + 1e-6f);                     // eps on std
        asm volatile("" ::: "memory");   // forbid CSE of pass-1 reads
        #pragma unroll
        for (int kt = 0; kt < 8; ++kt) {
            const int h0 = kt * 32 + g * 8;
            const f4 w0 = *(const f4*)(wi + h0), w1 = *(const f4*)(wi + h0 + 4);
            const f4 b0 = *(const f4*)(bi + h0), b1 = *(const f4*)(bi + h0 + 4);
            const f4 a0 = *(const f4*)(la + h0), a1 = *(const f4*)(la + h0 + 4);
            const f4 e0 = *(const f4*)(lb + h0), e1 = *(const f4*)(lb + h0 + 4);
            v8s a;
            #pragma unroll
            for (int i = 0; i < 4; ++i) {
                float v0 = __builtin_fmaf(tval, w0[i], b0[i]);
                float v1 = __builtin_fmaf(tval, w1[i], b1[i]);
                a[i]     = (short)f2bf(selu_f(v0 + (v0 - mean) * inv * a0[i] + e0[i]));
                a[i + 4] = (short)f2bf(selu_f(v1 + (v1 - mean) * inv * a1[i] + e1[i]));
            }
            *(v8s*)(actw + ((lr * 512 + h0 * 2) ^ (lr << 5))) = a;
        }
        asm volatile("s_waitcnt lgkmcnt(0)" ::: "memory");  // act wave-private
    }

    f4 acc[16];

    #pragma unroll 1
    for (int L = 0; L < 3; ++L) {
        const f4 zero = {0.f, 0.f, 0.f, 0.f};
        #pragma unroll
        for (int ct = 0; ct < 16; ++ct) {
            acc[ct] = zero;
            asm volatile("" : "+a"(acc[ct]));   // pin to AGPR side
        }

        #pragma unroll
        for (int s = 0; s < 8; ++s) {
            const int q = L * 8 + s;            // runtime (L not unrolled)
            // consume set s&1 into tile s&1 (compiler waits exactly on rr[s&1])
            convert_store(rr[s & 1], s & 1);
            if (q + 2 < 24) issue(rr[s & 1], q + 2);   // refill freed set
            FENCE_BAR();                         // tile s&1 visible to all
            // MFMA stage s: A from act (transient ds_read), B from tile s&1
            const v8s af = *(const v8s*)(actw + ((lr * 512 + (s * 32 + g * 8) * 2) ^ (lr << 5)));
            #pragma unroll
            for (int ct = 0; ct < 16; ++ct) {
                const int jb = ct * 16 + lr;
                int byte = ((s & 1) << 14) + ((g >> 1) << 13) + jb * 32 + ((g & 1) << 4);
                byte ^= ((jb >> 2) & 7) << 4;
                const v8s bf = *(const v8s*)(lds + byte);
                acc[ct] = __builtin_amdgcn_mfma_f32_16x16x32_bf16(af, bf, acc[ct], 0, 0, 0);
            }
        }

        // ---------------- epilogue (params from LDS) ----------------
        const float* bh = P + (7 + L) * 256;
        const float* la = P + (1 + L) * 256;
        const float* lb = P + (4 + L) * 256;

        float sums[4] = {0,0,0,0}, sqs[4] = {0,0,0,0};
        #pragma unroll
        for (int ct = 0; ct < 16; ++ct) {
            const float bias = bh[ct * 16 + lr];
            #pragma unroll
            for (int r = 0; r < 4; ++r) {
                float v = acc[ct][r] + bias;
                acc[ct][r] = v;
                sums[r] += v; sqs[r] += v * v;
            }
        }
        #pragma unroll
        for (int r = 0; r < 4; ++r)
            #pragma unroll
            for (int m = 1; m <= 8; m <<= 1) {
                sums[r] += __shfl_xor(sums[r], m);
                sqs[r]  += __shfl_xor(sqs[r],  m);
            }
        float mean[4], inv[4];
        #pragma unroll
        for (int r = 0; r < 4; ++r) {
            mean[r] = sums[r] * (1.f / 256.f);
            float var = (sqs[r] - sums[r] * sums[r] * (1.f / 256.f)) * (1.f / 255.f);
            inv[r] = 1.f / (sqrtf(var) + 1e-6f);
        }

        if (L < 2) {
            // C layout (row=4g+r, col=ct*16+lr) -> act (wave-private transpose);
            // next-layer loads (issued above) keep flying under this epilogue.
            #pragma unroll
            for (int ct = 0; ct < 16; ++ct) {
                const float a_ = la[ct * 16 + lr], b_ = lb[ct * 16 + lr];
                #pragma unroll
                for (int r = 0; r < 4; ++r) {
                    float v  = acc[ct][r];
                    float sv = selu_f(v + (v - mean[r]) * inv[r] * a_ + b_);
                    const int row = 4 * g + r;
                    *(unsigned short*)(actw + ((row * 512 + (ct * 16 + lr) * 2) ^ (row << 5)))
                        = f2bf(sv);
                }
            }
            asm volatile("s_waitcnt lgkmcnt(0)" ::: "memory");  // act writes done
            __builtin_amdgcn_sched_barrier(0);
        } else {
            // fused output layer
            const float bo = b_out[n];
            float ps[4] = {0,0,0,0};
            #pragma unroll
            for (int ct = 0; ct < 16; ++ct) {
                const float a_ = la[ct * 16 + lr], b_ = lb[ct * 16 + lr];
                const float w_ = P[ct * 16 + lr];   // wo
                #pragma unroll
                for (int r = 0; r < 4; ++r) {
                    float v  = acc[ct][r];
                    float sv = selu_f(v + (v - mean[r]) * inv[r] * a_ + b_);
                    ps[r] += sv * w_;
                }
            }
            #pragma unroll
            for (int r = 0; r < 4; ++r)
                #pragma unroll
                for (int m = 1; m <= 8; m <<= 1)
                    ps[r] += __shfl_xor(ps[r], m);
            #pragma unroll
            for (int r = 0; r < 4; ++r)
                if (lr == r)
                    basesT[(size_t)(wv * 16 + 4 * g + r) * NNET + n] = ps[r] + bo;
        }
    }
}

// score[b, jk] = sum_m x[b,m,jk>>1] * basesT[m][jk] * w[m]
__launch_bounds__(256)
__global__ void score_kernel(const float* __restrict__ x,
                             const float* __restrict__ t,
                             const float* __restrict__ basesT,
                             float* __restrict__ out)
{
    __shared__ float c_lds[M_GRID * 32];
    const int jt  = blockIdx.x;   // 0..4
    const int bt  = blockIdx.y;   // 0..255
    const int tid = threadIdx.x;

    for (int i = tid; i < M_GRID * 32; i += 256) {
        const int m  = i >> 5;
        const int jl = i & 31;
        const float tp = t[m == M_GRID - 1 ? M_GRID - 1 : m + 1];
        const float tm = t[m == 0 ? 0 : m - 1];
        c_lds[i] = basesT[(size_t)m * NNET + jt * 32 + jl] * 0.5f * (tp - tm);
    }
    __syncthreads();

    const int jj = tid & 31;
    const int bs = tid >> 5;
    const int jk = jt * 32 + jj;
    const int b  = bt * 8 + bs;
    const float* xp = x + (size_t)b * (M_GRID * J_FEAT) + (jk >> 1);
    float acc = 0.f;
    #pragma unroll 8
    for (int m = 0; m < M_GRID; ++m)
        acc += xp[(size_t)m * J_FEAT] * c_lds[m * 32 + jj];
    out[(size_t)b * NNET + jk] = acc;
}

extern "C" void kernel_launch(void* const* d_in, const int* in_sizes, int n_in,
                              void* d_out, int out_size, void* d_ws, size_t ws_size,
                              hipStream_t stream)
{
    const float* x     = (const float*)d_in[0];
    const float* t     = (const float*)d_in[1];
    const float* W_in  = (const float*)d_in[2];
    const float* b_in  = (const float*)d_in[3];
    const float* W_h   = (const float*)d_in[4];
    const float* b_h   = (const float*)d_in[5];
    const float* W_out = (const float*)d_in[6];
    const float* b_out = (const float*)d_in[7];
    const float* ln_a  = (const float*)d_in[8];
    const float* ln_b  = (const float*)d_in[9];
    float* basesT = (float*)d_ws;   // 128*160*4 = 80 KiB

    basis_kernel<<<dim3(NNET), dim3(512), 112640, stream>>>(
        t, W_in, b_in, W_h, b_h, W_out, b_out, ln_a, ln_b, basesT);
    score_kernel<<<dim3(5, 256), dim3(256), 0, stream>>>(
        x, t, basesT, (float*)d_out);
}

// Round 15
// 85.447 us; speedup vs baseline: 1.5299x; 1.5299x over previous
//
#include <hip/hip_runtime.h>
#include <math.h>

#define M_GRID 128
#define J_FEAT 80
#define NNET   160   // NBASE*J_FEAT
#define HDIM   256

typedef __attribute__((ext_vector_type(8))) short v8s;   // 8 bf16
typedef __attribute__((ext_vector_type(4))) float f4;    // MFMA accum / float4

__device__ __forceinline__ unsigned short f2bf(float f) {
    unsigned u = __float_as_uint(f);
    u += 0x7fffu + ((u >> 16) & 1u);   // round-to-nearest-even
    return (unsigned short)(u >> 16);
}

__device__ __forceinline__ float selu_f(float x) {
    const float SC = 1.0507009873554805f;
    const float AL = 1.6732632423543772f;
    return x > 0.f ? SC * x : SC * AL * (__expf(x) - 1.f);
}

#define FENCE_BAR() do { asm volatile("s_waitcnt lgkmcnt(0)" ::: "memory"); \
                         __builtin_amdgcn_sched_barrier(0);                 \
                         __builtin_amdgcn_s_barrier(); } while (0)

// One workgroup per network n. 512 threads = 8 waves, wave w owns rows
// 16w..16w+15.  ROUND-15 DELTA vs r14: the "+a" AGPR pins are REMOVED.
// Evidence (r3-r14): pinning 64 AGPRs makes the unified-file AGPR block
// round up to a 128-reg granule, capping arch VGPRs at 128 and forcing the
// rr[] staging sets to spill (WRITE_SIZE 29.7 MB in r14) -- the spill, not
// the schedule, has been the bottleneck in every VMEM-staging attempt.
// With no pins, budget at 2 waves/SIMD is 256 unified: acc 64 + rr 32 +
// temps ~60 fits.  Everything else identical to r14:
//  - W staged via ordinary VMEM register sets (global_load_lds issues only
//    ~1 KB/180cy/CU = the 11 GB/s wall seen r5-r10).
//  - act + params in LDS; one FENCE_BAR per K-stage; waits compiler-counted.
// LDS 110 KB: bf16 tiles 2x16K @0, act @32K (8x8K), params @96K.
__attribute__((amdgpu_flat_work_group_size(512, 512), amdgpu_waves_per_eu(2, 2)))
__global__ void basis_kernel(const float* __restrict__ t,
                             const float* __restrict__ W_in,
                             const float* __restrict__ b_in,
                             const float* __restrict__ W_h,
                             const float* __restrict__ b_h,
                             const float* __restrict__ W_out,
                             const float* __restrict__ b_out,
                             const float* __restrict__ ln_a,
                             const float* __restrict__ ln_b,
                             float* __restrict__ basesT)   // [M][NNET]
{
    extern __shared__ __align__(16) unsigned char lds[];   // 112640 B
    const int n    = blockIdx.x;
    const int tid  = threadIdx.x;
    const int l    = tid & 63;
    const int wv   = tid >> 6;      // wave 0..7
    const int lr   = l & 15;
    const int g    = l >> 4;        // k-group
    const int jcol = tid & 255;     // staging column
    const int o8   = tid >> 8;      // staging k-half (0/1)

    unsigned char* const actw = lds + 32768 + (size_t)wv * 8192;
    float* const P = (float*)(lds + 98304);
    // P groups (256 floats): 0=wo, 1-3=ln_a L1..3, 4-6=ln_b L1..3,
    // 7-9=b_h L0..2, 10=wi, 11=bi, 12=ln_a L0, 13=ln_b L0.

    // -------- staging helpers --------
    float rr[2][16];
    auto issue = [&](float (&r)[16], int q) {   // q = global stage 0..23
        const float* Wq = W_h + ((size_t)((q >> 3) * NNET + n) << 16)
                        + (size_t)((q & 7) * 32 + o8 * 16) * HDIM + jcol;
        #pragma unroll
        for (int i = 0; i < 16; ++i) r[i] = Wq[(size_t)i * HDIM];
    };
    auto convert_store = [&](float (&r)[16], int bufp) {
        #pragma unroll
        for (int o = 0; o < 2; ++o) {
            v8s pk;
            #pragma unroll
            for (int i = 0; i < 8; ++i) pk[i] = (short)f2bf(r[o * 8 + i]);
            int byte = (bufp << 14) + (o8 << 13) + jcol * 32 + (o << 4);
            byte ^= ((jcol >> 2) & 7) << 4;
            *(v8s*)(lds + byte) = pk;
        }
    };

    issue(rr[0], 0);        // in flight during param staging + input layer
    issue(rr[1], 1);

    // -------- params -> LDS --------
    {
        const size_t nb = (size_t)n * HDIM;
        #pragma unroll
        for (int i = 0; i < 7; ++i) {
            const int idx = tid + (i << 9), grp = idx >> 8, off = idx & 255;
            float v;
            if (grp == 0)       v = W_out[nb + off];
            else if (grp < 4)   v = ln_a[((size_t)grp * NNET + n) * HDIM + off];
            else if (grp < 7)   v = ln_b[((size_t)(grp - 3) * NNET + n) * HDIM + off];
            else if (grp < 10)  v = b_h[((size_t)(grp - 7) * NNET + n) * HDIM + off];
            else if (grp == 10) v = W_in[nb + off];
            else if (grp == 11) v = b_in[nb + off];
            else if (grp == 12) v = ln_a[nb + off];
            else                v = ln_b[nb + off];
            P[idx] = v;
        }
    }
    FENCE_BAR();   // params visible (raw barrier: rr loads stay in flight)

    // -------- input layer (LDS params; two passes; output straight to act) ----
    const float tval = t[wv * 16 + lr];
    {
        const float* wi = P + 2560; const float* bi = P + 2816;
        const float* la = P + 3072; const float* lb = P + 3328;
        float s_ = 0.f, q_ = 0.f;
        #pragma unroll
        for (int kt = 0; kt < 8; ++kt) {
            const int h0 = kt * 32 + g * 8;
            const f4 w0 = *(const f4*)(wi + h0), w1 = *(const f4*)(wi + h0 + 4);
            const f4 b0 = *(const f4*)(bi + h0), b1 = *(const f4*)(bi + h0 + 4);
            #pragma unroll
            for (int i = 0; i < 4; ++i) {
                float v0 = __builtin_fmaf(tval, w0[i], b0[i]);
                float v1 = __builtin_fmaf(tval, w1[i], b1[i]);
                s_ += v0 + v1; q_ += v0 * v0 + v1 * v1;
            }
        }
        s_ += __shfl_xor(s_, 16); q_ += __shfl_xor(q_, 16);
        s_ += __shfl_xor(s_, 32); q_ += __shfl_xor(q_, 32);
        const float mean = s_ * (1.f / 256.f);
        const float var  = (q_ - s_ * s_ * (1.f / 256.f)) * (1.f / 255.f); // unbiased
        const float inv  = 1.f / (sqrtf(var) + 1e-6f);                     // eps on std
        asm volatile("" ::: "memory");   // forbid CSE of pass-1 reads
        #pragma unroll
        for (int kt = 0; kt < 8; ++kt) {
            const int h0 = kt * 32 + g * 8;
            const f4 w0 = *(const f4*)(wi + h0), w1 = *(const f4*)(wi + h0 + 4);
            const f4 b0 = *(const f4*)(bi + h0), b1 = *(const f4*)(bi + h0 + 4);
            const f4 a0 = *(const f4*)(la + h0), a1 = *(const f4*)(la + h0 + 4);
            const f4 e0 = *(const f4*)(lb + h0), e1 = *(const f4*)(lb + h0 + 4);
            v8s a;
            #pragma unroll
            for (int i = 0; i < 4; ++i) {
                float v0 = __builtin_fmaf(tval, w0[i], b0[i]);
                float v1 = __builtin_fmaf(tval, w1[i], b1[i]);
                a[i]     = (short)f2bf(selu_f(v0 + (v0 - mean) * inv * a0[i] + e0[i]));
                a[i + 4] = (short)f2bf(selu_f(v1 + (v1 - mean) * inv * a1[i] + e1[i]));
            }
            *(v8s*)(actw + ((lr * 512 + h0 * 2) ^ (lr << 5))) = a;
        }
        asm volatile("s_waitcnt lgkmcnt(0)" ::: "memory");  // act wave-private
    }

    f4 acc[16];

    #pragma unroll 1
    for (int L = 0; L < 3; ++L) {
        const f4 zero = {0.f, 0.f, 0.f, 0.f};
        #pragma unroll
        for (int ct = 0; ct < 16; ++ct) acc[ct] = zero;   // no AGPR pin (r15)

        #pragma unroll
        for (int s = 0; s < 8; ++s) {
            const int q = L * 8 + s;            // runtime (L not unrolled)
            // consume set s&1 into tile s&1 (compiler waits exactly on rr[s&1])
            convert_store(rr[s & 1], s & 1);
            if (q + 2 < 24) issue(rr[s & 1], q + 2);   // refill freed set
            FENCE_BAR();                         // tile s&1 visible to all
            // MFMA stage s: A from act (transient ds_read), B from tile s&1
            const v8s af = *(const v8s*)(actw + ((lr * 512 + (s * 32 + g * 8) * 2) ^ (lr << 5)));
            #pragma unroll
            for (int ct = 0; ct < 16; ++ct) {
                const int jb = ct * 16 + lr;
                int byte = ((s & 1) << 14) + ((g >> 1) << 13) + jb * 32 + ((g & 1) << 4);
                byte ^= ((jb >> 2) & 7) << 4;
                const v8s bf = *(const v8s*)(lds + byte);
                acc[ct] = __builtin_amdgcn_mfma_f32_16x16x32_bf16(af, bf, acc[ct], 0, 0, 0);
            }
        }

        // ---------------- epilogue (params from LDS) ----------------
        const float* bh = P + (7 + L) * 256;
        const float* la = P + (1 + L) * 256;
        const float* lb = P + (4 + L) * 256;

        float sums[4] = {0,0,0,0}, sqs[4] = {0,0,0,0};
        #pragma unroll
        for (int ct = 0; ct < 16; ++ct) {
            const float bias = bh[ct * 16 + lr];
            #pragma unroll
            for (int r = 0; r < 4; ++r) {
                float v = acc[ct][r] + bias;
                acc[ct][r] = v;
                sums[r] += v; sqs[r] += v * v;
            }
        }
        #pragma unroll
        for (int r = 0; r < 4; ++r)
            #pragma unroll
            for (int m = 1; m <= 8; m <<= 1) {
                sums[r] += __shfl_xor(sums[r], m);
                sqs[r]  += __shfl_xor(sqs[r],  m);
            }
        float mean[4], inv[4];
        #pragma unroll
        for (int r = 0; r < 4; ++r) {
            mean[r] = sums[r] * (1.f / 256.f);
            float var = (sqs[r] - sums[r] * sums[r] * (1.f / 256.f)) * (1.f / 255.f);
            inv[r] = 1.f / (sqrtf(var) + 1e-6f);
        }

        if (L < 2) {
            // C layout (row=4g+r, col=ct*16+lr) -> act (wave-private transpose);
            // next-layer loads (issued above) keep flying under this epilogue.
            #pragma unroll
            for (int ct = 0; ct < 16; ++ct) {
                const float a_ = la[ct * 16 + lr], b_ = lb[ct * 16 + lr];
                #pragma unroll
                for (int r = 0; r < 4; ++r) {
                    float v  = acc[ct][r];
                    float sv = selu_f(v + (v - mean[r]) * inv[r] * a_ + b_);
                    const int row = 4 * g + r;
                    *(unsigned short*)(actw + ((row * 512 + (ct * 16 + lr) * 2) ^ (row << 5)))
                        = f2bf(sv);
                }
            }
            asm volatile("s_waitcnt lgkmcnt(0)" ::: "memory");  // act writes done
            __builtin_amdgcn_sched_barrier(0);
        } else {
            // fused output layer
            const float bo = b_out[n];
            float ps[4] = {0,0,0,0};
            #pragma unroll
            for (int ct = 0; ct < 16; ++ct) {
                const float a_ = la[ct * 16 + lr], b_ = lb[ct * 16 + lr];
                const float w_ = P[ct * 16 + lr];   // wo
                #pragma unroll
                for (int r = 0; r < 4; ++r) {
                    float v  = acc[ct][r];
                    float sv = selu_f(v + (v - mean[r]) * inv[r] * a_ + b_);
                    ps[r] += sv * w_;
                }
            }
            #pragma unroll
            for (int r = 0; r < 4; ++r)
                #pragma unroll
                for (int m = 1; m <= 8; m <<= 1)
                    ps[r] += __shfl_xor(ps[r], m);
            #pragma unroll
            for (int r = 0; r < 4; ++r)
                if (lr == r)
                    basesT[(size_t)(wv * 16 + 4 * g + r) * NNET + n] = ps[r] + bo;
        }
    }
}

// score[b, jk] = sum_m x[b,m,jk>>1] * basesT[m][jk] * w[m]
__launch_bounds__(256)
__global__ void score_kernel(const float* __restrict__ x,
                             const float* __restrict__ t,
                             const float* __restrict__ basesT,
                             float* __restrict__ out)
{
    __shared__ float c_lds[M_GRID * 32];
    const int jt  = blockIdx.x;   // 0..4
    const int bt  = blockIdx.y;   // 0..255
    const int tid = threadIdx.x;

    for (int i = tid; i < M_GRID * 32; i += 256) {
        const int m  = i >> 5;
        const int jl = i & 31;
        const float tp = t[m == M_GRID - 1 ? M_GRID - 1 : m + 1];
        const float tm = t[m == 0 ? 0 : m - 1];
        c_lds[i] = basesT[(size_t)m * NNET + jt * 32 + jl] * 0.5f * (tp - tm);
    }
    __syncthreads();

    const int jj = tid & 31;
    const int bs = tid >> 5;
    const int jk = jt * 32 + jj;
    const int b  = bt * 8 + bs;
    const float* xp = x + (size_t)b * (M_GRID * J_FEAT) + (jk >> 1);
    float acc = 0.f;
    #pragma unroll 8
    for (int m = 0; m < M_GRID; ++m)
        acc += xp[(size_t)m * J_FEAT] * c_lds[m * 32 + jj];
    out[(size_t)b * NNET + jk] = acc;
}

extern "C" void kernel_launch(void* const* d_in, const int* in_sizes, int n_in,
                              void* d_out, int out_size, void* d_ws, size_t ws_size,
                              hipStream_t stream)
{
    const float* x     = (const float*)d_in[0];
    const float* t     = (const float*)d_in[1];
    const float* W_in  = (const float*)d_in[2];
    const float* b_in  = (const float*)d_in[3];
    const float* W_h   = (const float*)d_in[4];
    const float* b_h   = (const float*)d_in[5];
    const float* W_out = (const float*)d_in[6];
    const float* b_out = (const float*)d_in[7];
    const float* ln_a  = (const float*)d_in[8];
    const float* ln_b  = (const float*)d_in[9];
    float* basesT = (float*)d_ws;   // 128*160*4 = 80 KiB

    basis_kernel<<<dim3(NNET), dim3(512), 112640, stream>>>(
        t, W_in, b_in, W_h, b_h, W_out, b_out, ln_a, ln_b, basesT);
    score_kernel<<<dim3(5, 256), dim3(256), 0, stream>>>(
        x, t, basesT, (float*)d_out);
}